// Round 1
// baseline (2242.948 us; speedup 1.0000x reference)
//
#include <hip/hip_runtime.h>

#define APAD 80  // LDS row stride (floats): 80%4==0 (b128-aligned), 80%32==16 -> 2-way conflict (free)

// ---------- tiny time/condition MLPs ----------
__global__ void k_tc(const float* __restrict__ t, const float* __restrict__ cond,
                     const float* __restrict__ tw1, const float* __restrict__ tb1,
                     const float* __restrict__ tw2, const float* __restrict__ tb2,
                     const float* __restrict__ cw1, const float* __restrict__ cb1,
                     const float* __restrict__ cw2, const float* __restrict__ cb2,
                     float* __restrict__ tf, float* __restrict__ cf, int B, int CDIM)
{
    __shared__ float hidT[8][128];
    __shared__ float hidC[8][128];
    int j = threadIdx.x;
    for (int b = 0; b < B; ++b) {
        hidT[b][j] = fmaxf(t[b] * tw1[j] + tb1[j], 0.f);
        float s = cb1[j];
        for (int d = 0; d < CDIM; ++d) s += cond[b * CDIM + d] * cw1[d * 128 + j];
        hidC[b][j] = fmaxf(s, 0.f);
    }
    __syncthreads();
    for (int b = 0; b < B; ++b) {
        float s1 = tb2[j], s2 = cb2[j];
        for (int k = 0; k < 128; ++k) {
            s1 += hidT[b][k] * tw2[k * 128 + j];
            s2 += hidC[b][k] * cw2[k * 128 + j];
        }
        tf[b * 128 + j] = s1;
        cf[b * 128 + j] = s2;
    }
}

// ---------- degree count ----------
__global__ void k_count(const int* __restrict__ dst, int* __restrict__ cnt, int E)
{
    int e = blockIdx.x * 256 + threadIdx.x;
    if (e < E) atomicAdd(&cnt[dst[e]], 1);
}

// ---------- scan (3 kernels) ----------
__global__ void k_scan1(const int* __restrict__ cnt, int* __restrict__ bsum, int N)
{
    __shared__ int s[256];
    int i = blockIdx.x * 256 + threadIdx.x;
    s[threadIdx.x] = (i < N) ? cnt[i] : 0;
    __syncthreads();
    for (int d = 128; d > 0; d >>= 1) {
        if (threadIdx.x < d) s[threadIdx.x] += s[threadIdx.x + d];
        __syncthreads();
    }
    if (threadIdx.x == 0) bsum[blockIdx.x] = s[0];
}

__global__ void k_scan2(const int* __restrict__ bsum, int* __restrict__ boff, int NB)
{
    __shared__ int s[512];
    int t = threadIdx.x;
    int v = (t < NB) ? bsum[t] : 0;
    s[t] = v;
    __syncthreads();
    for (int d = 1; d < 512; d <<= 1) {
        int x = (t >= d) ? s[t - d] : 0;
        __syncthreads();
        s[t] += x;
        __syncthreads();
    }
    if (t < NB) boff[t] = s[t] - v;  // exclusive block offset
}

__global__ void k_scan3(const int* __restrict__ cnt, const int* __restrict__ boff,
                        int* __restrict__ off, int N)
{
    __shared__ int s[256];
    int t = threadIdx.x;
    int i = blockIdx.x * 256 + t;
    int v = (i < N) ? cnt[i] : 0;
    s[t] = v;
    __syncthreads();
    for (int d = 1; d < 256; d <<= 1) {
        int x = (t >= d) ? s[t - d] : 0;
        __syncthreads();
        s[t] += x;
        __syncthreads();
    }
    if (i < N) off[i] = boff[blockIdx.x] + s[t] - v;
}

// ---------- CSR fill ----------
__global__ void k_fill(const int* __restrict__ src, const int* __restrict__ dst,
                       const float* __restrict__ ea, const int* __restrict__ off,
                       int* __restrict__ cur, int* __restrict__ csr_src,
                       float* __restrict__ csr_ea, int E)
{
    int e = blockIdx.x * 256 + threadIdx.x;
    if (e < E) {
        int d = dst[e];
        int r = atomicAdd(&cur[d], 1);
        int pos = off[d] + r;
        csr_src[pos] = src[e];
        csr_ea[pos]  = ea[e];
    }
}

// ---------- input MLP + time/cond add: h = mlp2(x) + tf[batch] + cf[batch] ----------
__global__ __launch_bounds__(256) void k_input(
    const float* __restrict__ x, const int* __restrict__ batch,
    const float* __restrict__ w1, const float* __restrict__ b1,
    const float* __restrict__ w2, const float* __restrict__ b2,
    const float* __restrict__ tf, const float* __restrict__ cf,
    float* __restrict__ h, int N)
{
    __shared__ float hT[128 * APAD];
    __shared__ float xs[64 * 3];
    __shared__ int   bs[64];
    int bn0 = blockIdx.x * 64;
    int t = threadIdx.x;
    if (t < 192) {
        int nn = t / 3, d = t - nn * 3;
        int n = bn0 + nn;
        xs[t] = (n < N) ? x[(size_t)n * 3 + d] : 0.f;
    }
    if (t < 64) {
        int n = bn0 + t;
        bs[t] = (n < N) ? batch[n] : 0;
    }
    __syncthreads();
    for (int idx = t; idx < 64 * 128; idx += 256) {
        int nn = idx >> 7, k = idx & 127;
        float hid = fmaxf(xs[nn * 3] * w1[k] + xs[nn * 3 + 1] * w1[128 + k]
                          + xs[nn * 3 + 2] * w1[256 + k] + b1[k], 0.f);
        hT[k * APAD + nn] = hid;
    }
    __syncthreads();
    int tx = t & 15, ty = t >> 4;
    int j0 = tx * 8, n0 = ty * 4;
    float acc[4][8];
    #pragma unroll
    for (int a = 0; a < 4; ++a)
        #pragma unroll
        for (int b = 0; b < 8; ++b) acc[a][b] = 0.f;
    for (int k = 0; k < 128; ++k) {
        float4 w0 = *(const float4*)&w2[k * 128 + j0];
        float4 w1v = *(const float4*)&w2[k * 128 + j0 + 4];
        float4 hv = *(const float4*)&hT[k * APAD + n0];
        float wv[8] = {w0.x, w0.y, w0.z, w0.w, w1v.x, w1v.y, w1v.z, w1v.w};
        float hvv[4] = {hv.x, hv.y, hv.z, hv.w};
        #pragma unroll
        for (int nn = 0; nn < 4; ++nn)
            #pragma unroll
            for (int jj = 0; jj < 8; ++jj)
                acc[nn][jj] = fmaf(hvv[nn], wv[jj], acc[nn][jj]);
    }
    float bb[8];
    #pragma unroll
    for (int jj = 0; jj < 8; ++jj) bb[jj] = b2[j0 + jj];
    for (int nn = 0; nn < 4; ++nn) {
        int n = bn0 + n0 + nn;
        if (n >= N) continue;
        int b = bs[n0 + nn];
        const float* tfp = &tf[b * 128 + j0];
        const float* cfp = &cf[b * 128 + j0];
        float o[8];
        #pragma unroll
        for (int jj = 0; jj < 8; ++jj) o[jj] = acc[nn][jj] + bb[jj] + tfp[jj] + cfp[jj];
        float4 o0 = {o[0], o[1], o[2], o[3]}, o1 = {o[4], o[5], o[6], o[7]};
        *(float4*)&h[(size_t)n * 128 + j0] = o0;
        *(float4*)&h[(size_t)n * 128 + j0 + 4] = o1;
    }
}

// ---------- per-layer: P = h@W1a + b1, Q = h@W1b ----------
__global__ __launch_bounds__(256) void k_pq(
    const float* __restrict__ h, const float* __restrict__ W1, const float* __restrict__ b1,
    float* __restrict__ P, float* __restrict__ Q, int N)
{
    __shared__ float hT[128 * APAD];
    int bn0 = blockIdx.x * 64;
    int t = threadIdx.x;
    for (int idx = t; idx < 64 * 128; idx += 256) {
        int nn = idx >> 7, k = idx & 127;
        int n = bn0 + nn;
        hT[k * APAD + nn] = (n < N) ? h[(size_t)n * 128 + k] : 0.f;
    }
    __syncthreads();
    int tx = t & 31, ty = t >> 5;   // tx: 32 col-groups over 256 concat cols, ty: 8 node-groups
    int j0 = tx * 8, n0 = ty * 8;
    bool isP = (j0 < 128);
    const float* Wb = isP ? (W1 + j0) : (W1 + 128 * 128 + (j0 - 128));
    float acc[8][8];
    #pragma unroll
    for (int a = 0; a < 8; ++a)
        #pragma unroll
        for (int b = 0; b < 8; ++b) acc[a][b] = 0.f;
    for (int k = 0; k < 128; ++k) {
        const float* wr = Wb + k * 128;
        float4 w0 = *(const float4*)wr;
        float4 w1v = *(const float4*)(wr + 4);
        const float* hp = &hT[k * APAD + n0];
        float4 h0 = *(const float4*)hp;
        float4 h1 = *(const float4*)(hp + 4);
        float wv[8] = {w0.x, w0.y, w0.z, w0.w, w1v.x, w1v.y, w1v.z, w1v.w};
        float hvv[8] = {h0.x, h0.y, h0.z, h0.w, h1.x, h1.y, h1.z, h1.w};
        #pragma unroll
        for (int nn = 0; nn < 8; ++nn)
            #pragma unroll
            for (int jj = 0; jj < 8; ++jj)
                acc[nn][jj] = fmaf(hvv[nn], wv[jj], acc[nn][jj]);
    }
    float bias[8];
    #pragma unroll
    for (int jj = 0; jj < 8; ++jj) bias[jj] = isP ? b1[j0 + jj] : 0.f;
    float* outp = isP ? P : Q;
    int jo = isP ? j0 : (j0 - 128);
    for (int nn = 0; nn < 8; ++nn) {
        int n = bn0 + n0 + nn;
        if (n >= N) continue;
        float4 o0 = {acc[nn][0] + bias[0], acc[nn][1] + bias[1], acc[nn][2] + bias[2], acc[nn][3] + bias[3]};
        float4 o1 = {acc[nn][4] + bias[4], acc[nn][5] + bias[5], acc[nn][6] + bias[6], acc[nn][7] + bias[7]};
        *(float4*)&outp[(size_t)n * 128 + jo] = o0;
        *(float4*)&outp[(size_t)n * 128 + jo + 4] = o1;
    }
}

// ---------- per-layer edge aggregation: S[n] = mean_{e->n} relu(P[n]+Q[src]+ea*w1c)  (S aliases P) ----------
__global__ __launch_bounds__(256) void k_edge(
    float* __restrict__ PS, const float* __restrict__ Q,
    const int* __restrict__ csr_src, const float* __restrict__ csr_ea,
    const int* __restrict__ off, const int* __restrict__ cnt,
    const float* __restrict__ W1, int N)
{
    int n = blockIdx.x * 4 + (threadIdx.x >> 6);
    int lane = threadIdx.x & 63;
    if (n >= N) return;
    int deg = cnt[n];
    int base = off[n];
    const float* w1c = W1 + 256 * 128;
    float2 p = *(const float2*)&PS[(size_t)n * 128 + lane * 2];
    float2 w = *(const float2*)&w1c[lane * 2];
    float accx = 0.f, accy = 0.f;
    int s = 0; float ea = 0.f;
    if (deg > 0) { s = csr_src[base]; ea = csr_ea[base]; }
    for (int e = 0; e < deg; ++e) {
        float2 q = *(const float2*)&Q[(size_t)s * 128 + lane * 2];
        float eac = ea;
        if (e + 1 < deg) { s = csr_src[base + e + 1]; ea = csr_ea[base + e + 1]; }
        float z0 = p.x + q.x + eac * w.x;
        float z1 = p.y + q.y + eac * w.y;
        accx += fmaxf(z0, 0.f);
        accy += fmaxf(z1, 0.f);
    }
    float invc = 1.f / (float)max(deg, 1);
    float2 o = {accx * invc, accy * invc};
    *(float2*)&PS[(size_t)n * 128 + lane * 2] = o;
}

// ---------- per-layer: h += relu(S@W2 + b2) (guarded by cnt>0) ----------
__global__ __launch_bounds__(256) void k_update(
    float* __restrict__ h, const float* __restrict__ S, const int* __restrict__ cnt,
    const float* __restrict__ W2, const float* __restrict__ b2, int N)
{
    __shared__ float sT[128 * APAD];
    int bn0 = blockIdx.x * 64;
    int t = threadIdx.x;
    for (int idx = t; idx < 64 * 128; idx += 256) {
        int nn = idx >> 7, k = idx & 127;
        int n = bn0 + nn;
        sT[k * APAD + nn] = (n < N) ? S[(size_t)n * 128 + k] : 0.f;
    }
    __syncthreads();
    int tx = t & 15, ty = t >> 4;
    int j0 = tx * 8, n0 = ty * 4;
    float acc[4][8];
    #pragma unroll
    for (int a = 0; a < 4; ++a)
        #pragma unroll
        for (int b = 0; b < 8; ++b) acc[a][b] = 0.f;
    for (int k = 0; k < 128; ++k) {
        float4 w0 = *(const float4*)&W2[k * 128 + j0];
        float4 w1v = *(const float4*)&W2[k * 128 + j0 + 4];
        float4 sv = *(const float4*)&sT[k * APAD + n0];
        float wv[8] = {w0.x, w0.y, w0.z, w0.w, w1v.x, w1v.y, w1v.z, w1v.w};
        float svv[4] = {sv.x, sv.y, sv.z, sv.w};
        #pragma unroll
        for (int nn = 0; nn < 4; ++nn)
            #pragma unroll
            for (int jj = 0; jj < 8; ++jj)
                acc[nn][jj] = fmaf(svv[nn], wv[jj], acc[nn][jj]);
    }
    float bb[8];
    #pragma unroll
    for (int jj = 0; jj < 8; ++jj) bb[jj] = b2[j0 + jj];
    for (int nn = 0; nn < 4; ++nn) {
        int n = bn0 + n0 + nn;
        if (n >= N) continue;
        int c = cnt[n];
        float4 h0 = *(float4*)&h[(size_t)n * 128 + j0];
        float4 h1 = *(float4*)&h[(size_t)n * 128 + j0 + 4];
        float hv[8] = {h0.x, h0.y, h0.z, h0.w, h1.x, h1.y, h1.z, h1.w};
        float o[8];
        #pragma unroll
        for (int jj = 0; jj < 8; ++jj) {
            float agg = acc[nn][jj] + bb[jj];
            float r = (c > 0) ? fmaxf(agg, 0.f) : 0.f;
            o[jj] = hv[jj] + r;
        }
        float4 o0 = {o[0], o[1], o[2], o[3]}, o1 = {o[4], o[5], o[6], o[7]};
        *(float4*)&h[(size_t)n * 128 + j0] = o0;
        *(float4*)&h[(size_t)n * 128 + j0 + 4] = o1;
    }
}

// ---------- output MLP ----------
__global__ __launch_bounds__(256) void k_output(
    const float* __restrict__ h, const float* __restrict__ w1, const float* __restrict__ b1,
    const float* __restrict__ w2, const float* __restrict__ b2,
    float* __restrict__ out, int N)
{
    __shared__ float hT[128 * APAD];
    int bn0 = blockIdx.x * 64;
    int t = threadIdx.x;
    for (int idx = t; idx < 64 * 128; idx += 256) {
        int nn = idx >> 7, k = idx & 127;
        int n = bn0 + nn;
        hT[k * APAD + nn] = (n < N) ? h[(size_t)n * 128 + k] : 0.f;
    }
    __syncthreads();
    int tx = t & 15, ty = t >> 4;
    int j0 = tx * 8, n0 = ty * 4;
    float acc[4][8];
    #pragma unroll
    for (int a = 0; a < 4; ++a)
        #pragma unroll
        for (int b = 0; b < 8; ++b) acc[a][b] = 0.f;
    for (int k = 0; k < 128; ++k) {
        float4 w0 = *(const float4*)&w1[k * 128 + j0];
        float4 w1v = *(const float4*)&w1[k * 128 + j0 + 4];
        float4 hv = *(const float4*)&hT[k * APAD + n0];
        float wv[8] = {w0.x, w0.y, w0.z, w0.w, w1v.x, w1v.y, w1v.z, w1v.w};
        float hvv[4] = {hv.x, hv.y, hv.z, hv.w};
        #pragma unroll
        for (int nn = 0; nn < 4; ++nn)
            #pragma unroll
            for (int jj = 0; jj < 8; ++jj)
                acc[nn][jj] = fmaf(hvv[nn], wv[jj], acc[nn][jj]);
    }
    __syncthreads();  // all hT reads done
    // write hidden = relu(acc + b1) transposed into hT[j][nn]
    for (int nn = 0; nn < 4; ++nn) {
        #pragma unroll
        for (int jj = 0; jj < 8; ++jj)
            hT[(j0 + jj) * APAD + (n0 + nn)] = fmaxf(acc[nn][jj] + b1[j0 + jj], 0.f);
    }
    __syncthreads();
    if (t < 192) {
        int nn = t / 3, d = t - nn * 3;
        int n = bn0 + nn;
        if (n < N) {
            float s = b2[d];
            for (int j = 0; j < 128; ++j) s += hT[j * APAD + nn] * w2[j * 3 + d];
            out[(size_t)n * 3 + d] = s;
        }
    }
}

extern "C" void kernel_launch(void* const* d_in, const int* in_sizes, int n_in,
                              void* d_out, int out_size, void* d_ws, size_t ws_size,
                              hipStream_t stream)
{
    const float* x         = (const float*)d_in[0];
    const int*   edge_idx  = (const int*)d_in[1];
    const float* edge_attr = (const float*)d_in[2];
    const float* tt        = (const float*)d_in[3];
    const int*   batch     = (const int*)d_in[4];
    const float* cond      = (const float*)d_in[5];
    const float* in_w1 = (const float*)d_in[6],  *in_b1 = (const float*)d_in[7];
    const float* in_w2 = (const float*)d_in[8],  *in_b2 = (const float*)d_in[9];
    const float* t_w1  = (const float*)d_in[10], *t_b1  = (const float*)d_in[11];
    const float* t_w2  = (const float*)d_in[12], *t_b2  = (const float*)d_in[13];
    const float* c_w1  = (const float*)d_in[14], *c_b1  = (const float*)d_in[15];
    const float* c_w2  = (const float*)d_in[16], *c_b2  = (const float*)d_in[17];
    const float* convW1 = (const float*)d_in[18], *convb1 = (const float*)d_in[19];
    const float* convW2 = (const float*)d_in[20], *convb2 = (const float*)d_in[21];
    const float* out_w1 = (const float*)d_in[22], *out_b1 = (const float*)d_in[23];
    const float* out_w2 = (const float*)d_in[24], *out_b2 = (const float*)d_in[25];

    const int N = in_sizes[0] / 3;
    const int E = in_sizes[1] / 2;
    const int B = in_sizes[3];
    const int CDIM = in_sizes[5] / B;
    const int L = in_sizes[19] / 128;

    const int* esrc = edge_idx;
    const int* edst = edge_idx + E;

    char* w = (char*)d_ws;
    auto alloc = [&](size_t bytes) -> char* {
        char* p = w;
        w += (bytes + 255) & ~(size_t)255;
        return p;
    };
    float* h       = (float*)alloc((size_t)N * 128 * 4);
    float* P       = (float*)alloc((size_t)N * 128 * 4);   // also S (aliased)
    float* Q       = (float*)alloc((size_t)N * 128 * 4);
    int*   cnt     = (int*)alloc((size_t)N * 4);
    int*   cur     = (int*)alloc((size_t)N * 4);
    int*   off     = (int*)alloc((size_t)N * 4);
    int*   bsum    = (int*)alloc(4096);
    int*   boff    = (int*)alloc(4096);
    int*   csr_src = (int*)alloc((size_t)E * 4);
    float* csr_ea  = (float*)alloc((size_t)E * 4);
    float* tf      = (float*)alloc((size_t)B * 128 * 4);
    float* cf      = (float*)alloc((size_t)B * 128 * 4);

    hipMemsetAsync(cnt, 0, (size_t)N * 4, stream);
    hipMemsetAsync(cur, 0, (size_t)N * 4, stream);

    k_tc<<<1, 128, 0, stream>>>(tt, cond, t_w1, t_b1, t_w2, t_b2,
                                c_w1, c_b1, c_w2, c_b2, tf, cf, B, CDIM);

    const int eb = (E + 255) / 256;
    const int nb = (N + 255) / 256;
    k_count<<<eb, 256, 0, stream>>>(edst, cnt, E);
    k_scan1<<<nb, 256, 0, stream>>>(cnt, bsum, N);
    k_scan2<<<1, 512, 0, stream>>>(bsum, boff, nb);
    k_scan3<<<nb, 256, 0, stream>>>(cnt, boff, off, N);
    k_fill<<<eb, 256, 0, stream>>>(esrc, edst, edge_attr, off, cur, csr_src, csr_ea, E);

    const int gnodes = (N + 63) / 64;
    k_input<<<gnodes, 256, 0, stream>>>(x, batch, in_w1, in_b1, in_w2, in_b2, tf, cf, h, N);

    for (int i = 0; i < L; ++i) {
        const float* W1 = convW1 + (size_t)i * 257 * 128;
        const float* b1 = convb1 + (size_t)i * 128;
        const float* W2 = convW2 + (size_t)i * 128 * 128;
        const float* b2 = convb2 + (size_t)i * 128;
        k_pq<<<gnodes, 256, 0, stream>>>(h, W1, b1, P, Q, N);
        k_edge<<<(N + 3) / 4, 256, 0, stream>>>(P, Q, csr_src, csr_ea, off, cnt, W1, N);
        k_update<<<gnodes, 256, 0, stream>>>(h, P, cnt, W2, b2, N);
    }

    k_output<<<gnodes, 256, 0, stream>>>(h, out_w1, out_b1, out_w2, out_b2, (float*)d_out, N);
}

// Round 2
// 2141.148 us; speedup vs baseline: 1.0475x; 1.0475x over previous
//
#include <hip/hip_runtime.h>

#define APAD 80  // LDS row stride (floats): 80%4==0 (b128-aligned), 80%32==16 -> 2-way conflict (free)

// ---------- tiny time/condition MLPs ----------
__global__ void k_tc(const float* __restrict__ t, const float* __restrict__ cond,
                     const float* __restrict__ tw1, const float* __restrict__ tb1,
                     const float* __restrict__ tw2, const float* __restrict__ tb2,
                     const float* __restrict__ cw1, const float* __restrict__ cb1,
                     const float* __restrict__ cw2, const float* __restrict__ cb2,
                     float* __restrict__ tf, float* __restrict__ cf, int B, int CDIM)
{
    __shared__ float hidT[8][128];
    __shared__ float hidC[8][128];
    int j = threadIdx.x;
    for (int b = 0; b < B; ++b) {
        hidT[b][j] = fmaxf(t[b] * tw1[j] + tb1[j], 0.f);
        float s = cb1[j];
        for (int d = 0; d < CDIM; ++d) s += cond[b * CDIM + d] * cw1[d * 128 + j];
        hidC[b][j] = fmaxf(s, 0.f);
    }
    __syncthreads();
    for (int b = 0; b < B; ++b) {
        float s1 = tb2[j], s2 = cb2[j];
        for (int k = 0; k < 128; ++k) {
            s1 += hidT[b][k] * tw2[k * 128 + j];
            s2 += hidC[b][k] * cw2[k * 128 + j];
        }
        tf[b * 128 + j] = s1;
        cf[b * 128 + j] = s2;
    }
}

// ---------- degree count ----------
__global__ void k_count(const int* __restrict__ dst, int* __restrict__ cnt, int E)
{
    int e = blockIdx.x * 256 + threadIdx.x;
    if (e < E) atomicAdd(&cnt[dst[e]], 1);
}

// ---------- scan (3 kernels) ----------
__global__ void k_scan1(const int* __restrict__ cnt, int* __restrict__ bsum, int N)
{
    __shared__ int s[256];
    int i = blockIdx.x * 256 + threadIdx.x;
    s[threadIdx.x] = (i < N) ? cnt[i] : 0;
    __syncthreads();
    for (int d = 128; d > 0; d >>= 1) {
        if (threadIdx.x < d) s[threadIdx.x] += s[threadIdx.x + d];
        __syncthreads();
    }
    if (threadIdx.x == 0) bsum[blockIdx.x] = s[0];
}

__global__ void k_scan2(const int* __restrict__ bsum, int* __restrict__ boff, int NB)
{
    __shared__ int s[512];
    int t = threadIdx.x;
    int v = (t < NB) ? bsum[t] : 0;
    s[t] = v;
    __syncthreads();
    for (int d = 1; d < 512; d <<= 1) {
        int x = (t >= d) ? s[t - d] : 0;
        __syncthreads();
        s[t] += x;
        __syncthreads();
    }
    if (t < NB) boff[t] = s[t] - v;  // exclusive block offset
}

__global__ void k_scan3(const int* __restrict__ cnt, const int* __restrict__ boff,
                        int* __restrict__ off, int N)
{
    __shared__ int s[256];
    int t = threadIdx.x;
    int i = blockIdx.x * 256 + t;
    int v = (i < N) ? cnt[i] : 0;
    s[t] = v;
    __syncthreads();
    for (int d = 1; d < 256; d <<= 1) {
        int x = (t >= d) ? s[t - d] : 0;
        __syncthreads();
        s[t] += x;
        __syncthreads();
    }
    if (i < N) off[i] = boff[blockIdx.x] + s[t] - v;
}

// ---------- CSR fill (packed {src, ea}) ----------
__global__ void k_fill(const int* __restrict__ src, const int* __restrict__ dst,
                       const float* __restrict__ ea, const int* __restrict__ off,
                       int* __restrict__ cur, int2* __restrict__ csr, int E)
{
    int e = blockIdx.x * 256 + threadIdx.x;
    if (e < E) {
        int d = dst[e];
        int r = atomicAdd(&cur[d], 1);
        int2 v;
        v.x = src[e];
        v.y = __float_as_int(ea[e]);
        csr[off[d] + r] = v;
    }
}

// ---------- shared GEMM phases ----------
// PQ phase: P = hT^T @ W1a + b1, Q = hT^T @ W1b   (hT is [128 x APAD] col-major tile)
__device__ __forceinline__ void pq_phase(const float* hT, const float* __restrict__ W1,
                                         const float* __restrict__ b1,
                                         float* P, float* Q, int bn0, int N, int t)
{
    int tx = t & 31, ty = t >> 5;   // 32 col-groups over 256 concat cols, 8 node-groups
    int j0 = tx * 8, n0 = ty * 8;
    bool isP = (j0 < 128);
    const float* Wb = isP ? (W1 + j0) : (W1 + 128 * 128 + (j0 - 128));
    float acc[8][8];
    #pragma unroll
    for (int a = 0; a < 8; ++a)
        #pragma unroll
        for (int b = 0; b < 8; ++b) acc[a][b] = 0.f;
    for (int k = 0; k < 128; ++k) {
        const float* wr = Wb + k * 128;
        float4 w0 = *(const float4*)wr;
        float4 w1v = *(const float4*)(wr + 4);
        const float* hp = &hT[k * APAD + n0];
        float4 h0 = *(const float4*)hp;
        float4 h1 = *(const float4*)(hp + 4);
        float wv[8] = {w0.x, w0.y, w0.z, w0.w, w1v.x, w1v.y, w1v.z, w1v.w};
        float hvv[8] = {h0.x, h0.y, h0.z, h0.w, h1.x, h1.y, h1.z, h1.w};
        #pragma unroll
        for (int nn = 0; nn < 8; ++nn)
            #pragma unroll
            for (int jj = 0; jj < 8; ++jj)
                acc[nn][jj] = fmaf(hvv[nn], wv[jj], acc[nn][jj]);
    }
    float bias[8];
    #pragma unroll
    for (int jj = 0; jj < 8; ++jj) bias[jj] = isP ? b1[j0 + jj] : 0.f;
    float* outp = isP ? P : Q;
    int jo = isP ? j0 : (j0 - 128);
    for (int nn = 0; nn < 8; ++nn) {
        int n = bn0 + n0 + nn;
        if (n >= N) continue;
        float4 o0 = {acc[nn][0] + bias[0], acc[nn][1] + bias[1], acc[nn][2] + bias[2], acc[nn][3] + bias[3]};
        float4 o1 = {acc[nn][4] + bias[4], acc[nn][5] + bias[5], acc[nn][6] + bias[6], acc[nn][7] + bias[7]};
        *(float4*)&outp[(size_t)n * 128 + jo] = o0;
        *(float4*)&outp[(size_t)n * 128 + jo + 4] = o1;
    }
}

// 128x128 GEMM from LDS tile: acc[4][8] per thread, tiling tx=t&15 (j0=tx*8), ty=t>>4 (n0=ty*4)
__device__ __forceinline__ void gemm_128(const float* hT, const float* __restrict__ W,
                                         float acc[4][8], int j0, int n0)
{
    for (int k = 0; k < 128; ++k) {
        float4 w0 = *(const float4*)&W[k * 128 + j0];
        float4 w1v = *(const float4*)&W[k * 128 + j0 + 4];
        float4 hv = *(const float4*)&hT[k * APAD + n0];
        float wv[8] = {w0.x, w0.y, w0.z, w0.w, w1v.x, w1v.y, w1v.z, w1v.w};
        float hvv[4] = {hv.x, hv.y, hv.z, hv.w};
        #pragma unroll
        for (int nn = 0; nn < 4; ++nn)
            #pragma unroll
            for (int jj = 0; jj < 8; ++jj)
                acc[nn][jj] = fmaf(hvv[nn], wv[jj], acc[nn][jj]);
    }
}

// ---------- input MLP + time/cond add + PQ of layer 0 ----------
__global__ __launch_bounds__(256, 2) void k_input_pq(
    const float* __restrict__ x, const int* __restrict__ batch,
    const float* __restrict__ w1, const float* __restrict__ b1,
    const float* __restrict__ w2, const float* __restrict__ b2,
    const float* __restrict__ tf, const float* __restrict__ cf,
    const float* __restrict__ W1n, const float* __restrict__ b1n,
    float* __restrict__ h, float* P, float* Q, int N)
{
    __shared__ float hT[128 * APAD];
    __shared__ float xs[64 * 3];
    __shared__ int   bs[64];
    int bn0 = blockIdx.x * 64;
    int t = threadIdx.x;
    if (t < 192) {
        int nn = t / 3, d = t - nn * 3;
        int n = bn0 + nn;
        xs[t] = (n < N) ? x[(size_t)n * 3 + d] : 0.f;
    }
    if (t < 64) {
        int n = bn0 + t;
        bs[t] = (n < N) ? batch[n] : 0;
    }
    __syncthreads();
    for (int idx = t; idx < 64 * 128; idx += 256) {
        int nn = idx >> 7, k = idx & 127;
        hT[k * APAD + nn] = fmaxf(xs[nn * 3] * w1[k] + xs[nn * 3 + 1] * w1[128 + k]
                                  + xs[nn * 3 + 2] * w1[256 + k] + b1[k], 0.f);
    }
    __syncthreads();
    int tx = t & 15, ty = t >> 4;
    int j0 = tx * 8, n0 = ty * 4;
    float acc[4][8];
    #pragma unroll
    for (int a = 0; a < 4; ++a)
        #pragma unroll
        for (int b = 0; b < 8; ++b) acc[a][b] = 0.f;
    gemm_128(hT, w2, acc, j0, n0);
    // h = acc + b2 + tf[batch] + cf[batch]
    float hn[4][8];
    #pragma unroll
    for (int nn = 0; nn < 4; ++nn) {
        int b = bs[n0 + nn];
        const float* tfp = &tf[b * 128 + j0];
        const float* cfp = &cf[b * 128 + j0];
        #pragma unroll
        for (int jj = 0; jj < 8; ++jj)
            hn[nn][jj] = acc[nn][jj] + b2[j0 + jj] + tfp[jj] + cfp[jj];
    }
    for (int nn = 0; nn < 4; ++nn) {
        int n = bn0 + n0 + nn;
        if (n >= N) continue;
        float4 o0 = {hn[nn][0], hn[nn][1], hn[nn][2], hn[nn][3]};
        float4 o1 = {hn[nn][4], hn[nn][5], hn[nn][6], hn[nn][7]};
        *(float4*)&h[(size_t)n * 128 + j0] = o0;
        *(float4*)&h[(size_t)n * 128 + j0 + 4] = o1;
    }
    __syncthreads();  // hidden-tile reads done
    #pragma unroll
    for (int nn = 0; nn < 4; ++nn)
        #pragma unroll
        for (int jj = 0; jj < 8; ++jj)
            hT[(j0 + jj) * APAD + (n0 + nn)] = hn[nn][jj];
    __syncthreads();
    pq_phase(hT, W1n, b1n, P, Q, bn0, N, t);
}

// ---------- per-layer edge aggregation: S[n] = mean_{e->n} relu(P[n]+Q[src]+ea*w1c)  (S aliases P) ----------
__global__ __launch_bounds__(256) void k_edge(
    float* PS, const float* __restrict__ Q,
    const int2* __restrict__ csr, const int* __restrict__ off, const int* __restrict__ cnt,
    const float* __restrict__ W1, int N)
{
    int n = blockIdx.x * 4 + (threadIdx.x >> 6);
    int lane = threadIdx.x & 63;
    if (n >= N) return;
    int deg = cnt[n];
    int base = off[n];
    const float* w1c = W1 + 256 * 128;
    float2 p = *(const float2*)&PS[(size_t)n * 128 + lane * 2];
    float2 w = *(const float2*)&w1c[lane * 2];
    const float* Ql = Q + lane * 2;
    float accx = 0.f, accy = 0.f;
    int e = 0;
    for (; e + 4 <= deg; e += 4) {
        int2 c0 = csr[base + e];
        int2 c1 = csr[base + e + 1];
        int2 c2 = csr[base + e + 2];
        int2 c3 = csr[base + e + 3];
        float2 q0 = *(const float2*)&Ql[(size_t)c0.x * 128];
        float2 q1 = *(const float2*)&Ql[(size_t)c1.x * 128];
        float2 q2 = *(const float2*)&Ql[(size_t)c2.x * 128];
        float2 q3 = *(const float2*)&Ql[(size_t)c3.x * 128];
        float e0 = __int_as_float(c0.y), e1 = __int_as_float(c1.y);
        float e2 = __int_as_float(c2.y), e3 = __int_as_float(c3.y);
        accx += fmaxf(p.x + q0.x + e0 * w.x, 0.f);
        accy += fmaxf(p.y + q0.y + e0 * w.y, 0.f);
        accx += fmaxf(p.x + q1.x + e1 * w.x, 0.f);
        accy += fmaxf(p.y + q1.y + e1 * w.y, 0.f);
        accx += fmaxf(p.x + q2.x + e2 * w.x, 0.f);
        accy += fmaxf(p.y + q2.y + e2 * w.y, 0.f);
        accx += fmaxf(p.x + q3.x + e3 * w.x, 0.f);
        accy += fmaxf(p.y + q3.y + e3 * w.y, 0.f);
    }
    for (; e < deg; ++e) {
        int2 c = csr[base + e];
        float2 q = *(const float2*)&Ql[(size_t)c.x * 128];
        float ec = __int_as_float(c.y);
        accx += fmaxf(p.x + q.x + ec * w.x, 0.f);
        accy += fmaxf(p.y + q.y + ec * w.y, 0.f);
    }
    float invc = 1.f / (float)max(deg, 1);
    float2 o = {accx * invc, accy * invc};
    *(float2*)&PS[(size_t)n * 128 + lane * 2] = o;
}

// ---------- fused: h += relu(S@W2 + b2) then P,Q = h@W1next + b1next  (S aliases P!) ----------
__global__ __launch_bounds__(256, 2) void k_fused(
    float* __restrict__ h, const float* S, const int* __restrict__ cnt,
    const float* __restrict__ W2, const float* __restrict__ b2,
    const float* __restrict__ W1n, const float* __restrict__ b1n,
    float* P, float* Q, int N)
{
    __shared__ float hT[128 * APAD];
    int bn0 = blockIdx.x * 64;
    int t = threadIdx.x;
    for (int idx = t; idx < 64 * 128; idx += 256) {
        int nn = idx >> 7, k = idx & 127;
        int n = bn0 + nn;
        hT[k * APAD + nn] = (n < N) ? S[(size_t)n * 128 + k] : 0.f;
    }
    __syncthreads();
    int tx = t & 15, ty = t >> 4;
    int j0 = tx * 8, n0 = ty * 4;
    float acc[4][8];
    #pragma unroll
    for (int a = 0; a < 4; ++a)
        #pragma unroll
        for (int b = 0; b < 8; ++b) acc[a][b] = 0.f;
    gemm_128(hT, W2, acc, j0, n0);
    float hn[4][8];
    for (int nn = 0; nn < 4; ++nn) {
        int n = bn0 + n0 + nn;
        if (n < N) {
            int c = cnt[n];
            float4 h0 = *(float4*)&h[(size_t)n * 128 + j0];
            float4 h1 = *(float4*)&h[(size_t)n * 128 + j0 + 4];
            float hv[8] = {h0.x, h0.y, h0.z, h0.w, h1.x, h1.y, h1.z, h1.w};
            #pragma unroll
            for (int jj = 0; jj < 8; ++jj) {
                float agg = acc[nn][jj] + b2[j0 + jj];
                float r = (c > 0) ? fmaxf(agg, 0.f) : 0.f;
                hn[nn][jj] = hv[jj] + r;
            }
            float4 o0 = {hn[nn][0], hn[nn][1], hn[nn][2], hn[nn][3]};
            float4 o1 = {hn[nn][4], hn[nn][5], hn[nn][6], hn[nn][7]};
            *(float4*)&h[(size_t)n * 128 + j0] = o0;
            *(float4*)&h[(size_t)n * 128 + j0 + 4] = o1;
        } else {
            #pragma unroll
            for (int jj = 0; jj < 8; ++jj) hn[nn][jj] = 0.f;
        }
    }
    __syncthreads();  // S-tile reads done
    #pragma unroll
    for (int nn = 0; nn < 4; ++nn)
        #pragma unroll
        for (int jj = 0; jj < 8; ++jj)
            hT[(j0 + jj) * APAD + (n0 + nn)] = hn[nn][jj];
    __syncthreads();
    pq_phase(hT, W1n, b1n, P, Q, bn0, N, t);
}

// ---------- final: h += relu(S@W2 + b2) then out = mlp2(h, out_w*, out_b*) ----------
__global__ __launch_bounds__(256, 2) void k_final(
    const float* __restrict__ h, const float* __restrict__ S, const int* __restrict__ cnt,
    const float* __restrict__ W2, const float* __restrict__ b2,
    const float* __restrict__ ow1, const float* __restrict__ ob1,
    const float* __restrict__ ow2, const float* __restrict__ ob2,
    float* __restrict__ out, int N)
{
    __shared__ float hT[128 * APAD];
    int bn0 = blockIdx.x * 64;
    int t = threadIdx.x;
    for (int idx = t; idx < 64 * 128; idx += 256) {
        int nn = idx >> 7, k = idx & 127;
        int n = bn0 + nn;
        hT[k * APAD + nn] = (n < N) ? S[(size_t)n * 128 + k] : 0.f;
    }
    __syncthreads();
    int tx = t & 15, ty = t >> 4;
    int j0 = tx * 8, n0 = ty * 4;
    float acc[4][8];
    #pragma unroll
    for (int a = 0; a < 4; ++a)
        #pragma unroll
        for (int b = 0; b < 8; ++b) acc[a][b] = 0.f;
    gemm_128(hT, W2, acc, j0, n0);
    float hn[4][8];
    for (int nn = 0; nn < 4; ++nn) {
        int n = bn0 + n0 + nn;
        if (n < N) {
            int c = cnt[n];
            float4 h0 = *(const float4*)&h[(size_t)n * 128 + j0];
            float4 h1 = *(const float4*)&h[(size_t)n * 128 + j0 + 4];
            float hv[8] = {h0.x, h0.y, h0.z, h0.w, h1.x, h1.y, h1.z, h1.w};
            #pragma unroll
            for (int jj = 0; jj < 8; ++jj) {
                float agg = acc[nn][jj] + b2[j0 + jj];
                float r = (c > 0) ? fmaxf(agg, 0.f) : 0.f;
                hn[nn][jj] = hv[jj] + r;
            }
        } else {
            #pragma unroll
            for (int jj = 0; jj < 8; ++jj) hn[nn][jj] = 0.f;
        }
    }
    __syncthreads();
    #pragma unroll
    for (int nn = 0; nn < 4; ++nn)
        #pragma unroll
        for (int jj = 0; jj < 8; ++jj)
            hT[(j0 + jj) * APAD + (n0 + nn)] = hn[nn][jj];
    __syncthreads();
    // hidden = relu(h @ ow1 + ob1)
    float acc2[4][8];
    #pragma unroll
    for (int a = 0; a < 4; ++a)
        #pragma unroll
        for (int b = 0; b < 8; ++b) acc2[a][b] = 0.f;
    gemm_128(hT, ow1, acc2, j0, n0);
    __syncthreads();
    #pragma unroll
    for (int nn = 0; nn < 4; ++nn)
        #pragma unroll
        for (int jj = 0; jj < 8; ++jj)
            hT[(j0 + jj) * APAD + (n0 + nn)] = fmaxf(acc2[nn][jj] + ob1[j0 + jj], 0.f);
    __syncthreads();
    if (t < 192) {
        int nn = t / 3, d = t - nn * 3;
        int n = bn0 + nn;
        if (n < N) {
            float s = ob2[d];
            for (int j = 0; j < 128; ++j) s += hT[j * APAD + nn] * ow2[j * 3 + d];
            out[(size_t)n * 3 + d] = s;
        }
    }
}

extern "C" void kernel_launch(void* const* d_in, const int* in_sizes, int n_in,
                              void* d_out, int out_size, void* d_ws, size_t ws_size,
                              hipStream_t stream)
{
    const float* x         = (const float*)d_in[0];
    const int*   edge_idx  = (const int*)d_in[1];
    const float* edge_attr = (const float*)d_in[2];
    const float* tt        = (const float*)d_in[3];
    const int*   batch     = (const int*)d_in[4];
    const float* cond      = (const float*)d_in[5];
    const float* in_w1 = (const float*)d_in[6],  *in_b1 = (const float*)d_in[7];
    const float* in_w2 = (const float*)d_in[8],  *in_b2 = (const float*)d_in[9];
    const float* t_w1  = (const float*)d_in[10], *t_b1  = (const float*)d_in[11];
    const float* t_w2  = (const float*)d_in[12], *t_b2  = (const float*)d_in[13];
    const float* c_w1  = (const float*)d_in[14], *c_b1  = (const float*)d_in[15];
    const float* c_w2  = (const float*)d_in[16], *c_b2  = (const float*)d_in[17];
    const float* convW1 = (const float*)d_in[18], *convb1 = (const float*)d_in[19];
    const float* convW2 = (const float*)d_in[20], *convb2 = (const float*)d_in[21];
    const float* out_w1 = (const float*)d_in[22], *out_b1 = (const float*)d_in[23];
    const float* out_w2 = (const float*)d_in[24], *out_b2 = (const float*)d_in[25];

    const int N = in_sizes[0] / 3;
    const int E = in_sizes[1] / 2;
    const int B = in_sizes[3];
    const int CDIM = in_sizes[5] / B;
    const int L = in_sizes[19] / 128;

    const int* esrc = edge_idx;
    const int* edst = edge_idx + E;

    char* w = (char*)d_ws;
    auto alloc = [&](size_t bytes) -> char* {
        char* p = w;
        w += (bytes + 255) & ~(size_t)255;
        return p;
    };
    float* h    = (float*)alloc((size_t)N * 128 * 4);
    float* P    = (float*)alloc((size_t)N * 128 * 4);   // also S (aliased)
    float* Q    = (float*)alloc((size_t)N * 128 * 4);
    int*   cnt  = (int*)alloc((size_t)N * 4);
    int*   cur  = (int*)alloc((size_t)N * 4);
    int*   off  = (int*)alloc((size_t)N * 4);
    int*   bsum = (int*)alloc(4096);
    int*   boff = (int*)alloc(4096);
    int2*  csr  = (int2*)alloc((size_t)E * 8);
    float* tf   = (float*)alloc((size_t)B * 128 * 4);
    float* cf   = (float*)alloc((size_t)B * 128 * 4);

    hipMemsetAsync(cnt, 0, (size_t)N * 4, stream);
    hipMemsetAsync(cur, 0, (size_t)N * 4, stream);

    k_tc<<<1, 128, 0, stream>>>(tt, cond, t_w1, t_b1, t_w2, t_b2,
                                c_w1, c_b1, c_w2, c_b2, tf, cf, B, CDIM);

    const int eb = (E + 255) / 256;
    const int nb = (N + 255) / 256;
    k_count<<<eb, 256, 0, stream>>>(edst, cnt, E);
    k_scan1<<<nb, 256, 0, stream>>>(cnt, bsum, N);
    k_scan2<<<1, 512, 0, stream>>>(bsum, boff, nb);
    k_scan3<<<nb, 256, 0, stream>>>(cnt, boff, off, N);
    k_fill<<<eb, 256, 0, stream>>>(esrc, edst, edge_attr, off, cur, csr, E);

    const int gnodes = (N + 63) / 64;
    k_input_pq<<<gnodes, 256, 0, stream>>>(x, batch, in_w1, in_b1, in_w2, in_b2,
                                           tf, cf, convW1, convb1, h, P, Q, N);

    for (int i = 0; i < L; ++i) {
        const float* W1 = convW1 + (size_t)i * 257 * 128;
        const float* b1 = convb1 + (size_t)i * 128;
        const float* W2 = convW2 + (size_t)i * 128 * 128;
        const float* b2 = convb2 + (size_t)i * 128;
        k_edge<<<(N + 3) / 4, 256, 0, stream>>>(P, Q, csr, off, cnt, W1, N);
        if (i < L - 1) {
            const float* W1n = convW1 + (size_t)(i + 1) * 257 * 128;
            const float* b1n = convb1 + (size_t)(i + 1) * 128;
            k_fused<<<gnodes, 256, 0, stream>>>(h, P, cnt, W2, b2, W1n, b1n, P, Q, N);
        } else {
            k_final<<<gnodes, 256, 0, stream>>>(h, P, cnt, W2, b2,
                                                out_w1, out_b1, out_w2, out_b2,
                                                (float*)d_out, N);
        }
    }
}

// Round 3
// 2060.836 us; speedup vs baseline: 1.0884x; 1.0390x over previous
//
#include <hip/hip_runtime.h>

#define LROW 132  // floats per LDS tile row: 528B stride, rows r/r+8 alias = 2-way (free)

// ---------- tiny time/condition MLPs ----------
__global__ void k_tc(const float* __restrict__ t, const float* __restrict__ cond,
                     const float* __restrict__ tw1, const float* __restrict__ tb1,
                     const float* __restrict__ tw2, const float* __restrict__ tb2,
                     const float* __restrict__ cw1, const float* __restrict__ cb1,
                     const float* __restrict__ cw2, const float* __restrict__ cb2,
                     float* __restrict__ tf, float* __restrict__ cf, int B, int CDIM)
{
    __shared__ float hidT[8][128];
    __shared__ float hidC[8][128];
    int j = threadIdx.x;
    for (int b = 0; b < B; ++b) {
        hidT[b][j] = fmaxf(t[b] * tw1[j] + tb1[j], 0.f);
        float s = cb1[j];
        for (int d = 0; d < CDIM; ++d) s += cond[b * CDIM + d] * cw1[d * 128 + j];
        hidC[b][j] = fmaxf(s, 0.f);
    }
    __syncthreads();
    for (int b = 0; b < B; ++b) {
        float s1 = tb2[j], s2 = cb2[j];
        for (int k = 0; k < 128; ++k) {
            s1 += hidT[b][k] * tw2[k * 128 + j];
            s2 += hidC[b][k] * cw2[k * 128 + j];
        }
        tf[b * 128 + j] = s1;
        cf[b * 128 + j] = s2;
    }
}

// ---------- degree count ----------
__global__ void k_count(const int* __restrict__ dst, int* __restrict__ cnt, int E)
{
    int e = blockIdx.x * 256 + threadIdx.x;
    if (e < E) atomicAdd(&cnt[dst[e]], 1);
}

// ---------- scan (3 kernels) ----------
__global__ void k_scan1(const int* __restrict__ cnt, int* __restrict__ bsum, int N)
{
    __shared__ int s[256];
    int i = blockIdx.x * 256 + threadIdx.x;
    s[threadIdx.x] = (i < N) ? cnt[i] : 0;
    __syncthreads();
    for (int d = 128; d > 0; d >>= 1) {
        if (threadIdx.x < d) s[threadIdx.x] += s[threadIdx.x + d];
        __syncthreads();
    }
    if (threadIdx.x == 0) bsum[blockIdx.x] = s[0];
}

__global__ void k_scan2(const int* __restrict__ bsum, int* __restrict__ boff, int NB)
{
    __shared__ int s[512];
    int t = threadIdx.x;
    int v = (t < NB) ? bsum[t] : 0;
    s[t] = v;
    __syncthreads();
    for (int d = 1; d < 512; d <<= 1) {
        int x = (t >= d) ? s[t - d] : 0;
        __syncthreads();
        s[t] += x;
        __syncthreads();
    }
    if (t < NB) boff[t] = s[t] - v;  // exclusive block offset
}

__global__ void k_scan3(const int* __restrict__ cnt, const int* __restrict__ boff,
                        int* __restrict__ off, int N)
{
    __shared__ int s[256];
    int t = threadIdx.x;
    int i = blockIdx.x * 256 + t;
    int v = (i < N) ? cnt[i] : 0;
    s[t] = v;
    __syncthreads();
    for (int d = 1; d < 256; d <<= 1) {
        int x = (t >= d) ? s[t - d] : 0;
        __syncthreads();
        s[t] += x;
        __syncthreads();
    }
    if (i < N) off[i] = boff[blockIdx.x] + s[t] - v;
}

// ---------- CSR fill (packed {src, ea}) ----------
__global__ void k_fill(const int* __restrict__ src, const int* __restrict__ dst,
                       const float* __restrict__ ea, const int* __restrict__ off,
                       int* __restrict__ cur, int2* __restrict__ csr, int E)
{
    int e = blockIdx.x * 256 + threadIdx.x;
    if (e < E) {
        int d = dst[e];
        int r = atomicAdd(&cur[d], 1);
        int2 v;
        v.x = src[e];
        v.y = __float_as_int(ea[e]);
        csr[off[d] + r] = v;
    }
}

// ---------- GEMM helpers ([n][LROW] row-major LDS tile) ----------

// stage 64 global rows of 128 -> LDS, coalesced float4, zero-pad OOB rows
__device__ __forceinline__ void stage_tile(float* lds, const float* __restrict__ g,
                                           int bn0, int N, int t)
{
    for (int i = t; i < 64 * 32; i += 256) {
        int nn = i >> 5, c4 = (i & 31) * 4;
        int n = bn0 + nn;
        float4 v = {0.f, 0.f, 0.f, 0.f};
        if (n < N) v = *(const float4*)&g[(size_t)n * 128 + c4];
        *(float4*)&lds[nn * LROW + c4] = v;
    }
}

// C[n0..n0+3][j0..j0+7] += A[n][k] * W[k][j], A from LDS rows, W from global
__device__ __forceinline__ void gemm4x8(const float* lds, const float* __restrict__ W,
                                        float acc[4][8], int j0, int n0)
{
    for (int k = 0; k < 128; k += 4) {
        float4 a0 = *(const float4*)&lds[(n0 + 0) * LROW + k];
        float4 a1 = *(const float4*)&lds[(n0 + 1) * LROW + k];
        float4 a2 = *(const float4*)&lds[(n0 + 2) * LROW + k];
        float4 a3 = *(const float4*)&lds[(n0 + 3) * LROW + k];
        const float* ap[4] = {(const float*)&a0, (const float*)&a1,
                              (const float*)&a2, (const float*)&a3};
        #pragma unroll
        for (int kk = 0; kk < 4; ++kk) {
            float4 w0 = *(const float4*)&W[(k + kk) * 128 + j0];
            float4 w1 = *(const float4*)&W[(k + kk) * 128 + j0 + 4];
            float wv[8] = {w0.x, w0.y, w0.z, w0.w, w1.x, w1.y, w1.z, w1.w};
            #pragma unroll
            for (int nn = 0; nn < 4; ++nn) {
                float av = ap[nn][kk];
                #pragma unroll
                for (int jj = 0; jj < 8; ++jj)
                    acc[nn][jj] = fmaf(av, wv[jj], acc[nn][jj]);
            }
        }
    }
}

// PQ phase: P = A @ W1a + b1, Q = A @ W1b; A = LDS tile rows
__device__ __forceinline__ void pq_phase(const float* lds, const float* __restrict__ W1,
                                         const float* __restrict__ b1,
                                         float* P, float* Q, int bn0, int N, int t)
{
    int tx = t & 31, ty = t >> 5;   // 32 col-groups over 256 concat cols, 8 node-groups
    int j0 = tx * 8, n0 = ty * 8;
    bool isP = (j0 < 128);
    const float* Wb = isP ? (W1 + j0) : (W1 + 128 * 128 + (j0 - 128));
    float acc[8][8];
    #pragma unroll
    for (int a = 0; a < 8; ++a)
        #pragma unroll
        for (int b = 0; b < 8; ++b) acc[a][b] = 0.f;
    for (int k = 0; k < 128; k += 4) {
        float4 a[8];
        #pragma unroll
        for (int nn = 0; nn < 8; ++nn)
            a[nn] = *(const float4*)&lds[(n0 + nn) * LROW + k];
        #pragma unroll
        for (int kk = 0; kk < 4; ++kk) {
            float4 w0 = *(const float4*)&Wb[(k + kk) * 128];
            float4 w1 = *(const float4*)&Wb[(k + kk) * 128 + 4];
            float wv[8] = {w0.x, w0.y, w0.z, w0.w, w1.x, w1.y, w1.z, w1.w};
            #pragma unroll
            for (int nn = 0; nn < 8; ++nn) {
                float av = ((const float*)&a[nn])[kk];
                #pragma unroll
                for (int jj = 0; jj < 8; ++jj)
                    acc[nn][jj] = fmaf(av, wv[jj], acc[nn][jj]);
            }
        }
    }
    float bias[8];
    #pragma unroll
    for (int jj = 0; jj < 8; ++jj) bias[jj] = isP ? b1[j0 + jj] : 0.f;
    float* outp = isP ? P : Q;
    int jo = isP ? j0 : (j0 - 128);
    for (int nn = 0; nn < 8; ++nn) {
        int n = bn0 + n0 + nn;
        if (n >= N) continue;
        float4 o0 = {acc[nn][0] + bias[0], acc[nn][1] + bias[1], acc[nn][2] + bias[2], acc[nn][3] + bias[3]};
        float4 o1 = {acc[nn][4] + bias[4], acc[nn][5] + bias[5], acc[nn][6] + bias[6], acc[nn][7] + bias[7]};
        *(float4*)&outp[(size_t)n * 128 + jo] = o0;
        *(float4*)&outp[(size_t)n * 128 + jo + 4] = o1;
    }
}

// ---------- input MLP + time/cond add + PQ of layer 0 ----------
__global__ __launch_bounds__(256, 4) void k_input_pq(
    const float* __restrict__ x, const int* __restrict__ batch,
    const float* __restrict__ w1, const float* __restrict__ b1,
    const float* __restrict__ w2, const float* __restrict__ b2,
    const float* __restrict__ tf, const float* __restrict__ cf,
    const float* __restrict__ W1n, const float* __restrict__ b1n,
    float* __restrict__ h, float* P, float* Q, int N)
{
    __shared__ float lds[64 * LROW];
    __shared__ float xs[64 * 3];
    __shared__ int   bs[64];
    int bn0 = blockIdx.x * 64;
    int t = threadIdx.x;
    if (t < 192) {
        int nn = t / 3, d = t - nn * 3;
        int n = bn0 + nn;
        xs[t] = (n < N) ? x[(size_t)n * 3 + d] : 0.f;
    }
    if (t < 64) {
        int n = bn0 + t;
        bs[t] = (n < N) ? batch[n] : 0;
    }
    __syncthreads();
    // hidden of input MLP: scalar writes, lanes span k -> conflict-free
    for (int idx = t; idx < 64 * 128; idx += 256) {
        int nn = idx >> 7, k = idx & 127;
        lds[nn * LROW + k] = fmaxf(xs[nn * 3] * w1[k] + xs[nn * 3 + 1] * w1[128 + k]
                                   + xs[nn * 3 + 2] * w1[256 + k] + b1[k], 0.f);
    }
    __syncthreads();
    int tx = t & 15, ty = t >> 4;
    int j0 = tx * 8, n0 = ty * 4;
    float acc[4][8];
    #pragma unroll
    for (int a = 0; a < 4; ++a)
        #pragma unroll
        for (int b = 0; b < 8; ++b) acc[a][b] = 0.f;
    gemm4x8(lds, w2, acc, j0, n0);
    float hn[4][8];
    #pragma unroll
    for (int nn = 0; nn < 4; ++nn) {
        int b = bs[n0 + nn];
        const float* tfp = &tf[b * 128 + j0];
        const float* cfp = &cf[b * 128 + j0];
        #pragma unroll
        for (int jj = 0; jj < 8; ++jj)
            hn[nn][jj] = acc[nn][jj] + b2[j0 + jj] + tfp[jj] + cfp[jj];
    }
    for (int nn = 0; nn < 4; ++nn) {
        int n = bn0 + n0 + nn;
        if (n >= N) continue;
        float4 o0 = {hn[nn][0], hn[nn][1], hn[nn][2], hn[nn][3]};
        float4 o1 = {hn[nn][4], hn[nn][5], hn[nn][6], hn[nn][7]};
        *(float4*)&h[(size_t)n * 128 + j0] = o0;
        *(float4*)&h[(size_t)n * 128 + j0 + 4] = o1;
    }
    __syncthreads();  // tile reads done
    #pragma unroll
    for (int nn = 0; nn < 4; ++nn) {
        float4 o0 = {hn[nn][0], hn[nn][1], hn[nn][2], hn[nn][3]};
        float4 o1 = {hn[nn][4], hn[nn][5], hn[nn][6], hn[nn][7]};
        *(float4*)&lds[(n0 + nn) * LROW + j0] = o0;
        *(float4*)&lds[(n0 + nn) * LROW + j0 + 4] = o1;
    }
    __syncthreads();
    pq_phase(lds, W1n, b1n, P, Q, bn0, N, t);
}

// ---------- per-layer edge aggregation: S[n] = mean_{e->n} relu(P[n]+Q[src]+ea*w1c)  (S aliases P) ----------
__global__ __launch_bounds__(256) void k_edge(
    float* PS, const float* __restrict__ Q,
    const int2* __restrict__ csr, const int* __restrict__ off, const int* __restrict__ cnt,
    const float* __restrict__ W1, int N)
{
    int n = blockIdx.x * 4 + (threadIdx.x >> 6);
    int lane = threadIdx.x & 63;
    if (n >= N) return;
    int deg = cnt[n];
    int base = off[n];
    const float* w1c = W1 + 256 * 128;
    float2 p = *(const float2*)&PS[(size_t)n * 128 + lane * 2];
    float2 w = *(const float2*)&w1c[lane * 2];
    const float* Ql = Q + lane * 2;
    float accx = 0.f, accy = 0.f;
    int e = 0;
    for (; e + 4 <= deg; e += 4) {
        int2 c0 = csr[base + e];
        int2 c1 = csr[base + e + 1];
        int2 c2 = csr[base + e + 2];
        int2 c3 = csr[base + e + 3];
        float2 q0 = *(const float2*)&Ql[(size_t)c0.x * 128];
        float2 q1 = *(const float2*)&Ql[(size_t)c1.x * 128];
        float2 q2 = *(const float2*)&Ql[(size_t)c2.x * 128];
        float2 q3 = *(const float2*)&Ql[(size_t)c3.x * 128];
        float e0 = __int_as_float(c0.y), e1 = __int_as_float(c1.y);
        float e2 = __int_as_float(c2.y), e3 = __int_as_float(c3.y);
        accx += fmaxf(p.x + q0.x + e0 * w.x, 0.f);
        accy += fmaxf(p.y + q0.y + e0 * w.y, 0.f);
        accx += fmaxf(p.x + q1.x + e1 * w.x, 0.f);
        accy += fmaxf(p.y + q1.y + e1 * w.y, 0.f);
        accx += fmaxf(p.x + q2.x + e2 * w.x, 0.f);
        accy += fmaxf(p.y + q2.y + e2 * w.y, 0.f);
        accx += fmaxf(p.x + q3.x + e3 * w.x, 0.f);
        accy += fmaxf(p.y + q3.y + e3 * w.y, 0.f);
    }
    for (; e < deg; ++e) {
        int2 c = csr[base + e];
        float2 q = *(const float2*)&Ql[(size_t)c.x * 128];
        float ec = __int_as_float(c.y);
        accx += fmaxf(p.x + q.x + ec * w.x, 0.f);
        accy += fmaxf(p.y + q.y + ec * w.y, 0.f);
    }
    float invc = 1.f / (float)max(deg, 1);
    float2 o = {accx * invc, accy * invc};
    *(float2*)&PS[(size_t)n * 128 + lane * 2] = o;
}

// ---------- fused: h += relu(S@W2 + b2) then P,Q = h@W1next + b1next  (S aliases P!) ----------
__global__ __launch_bounds__(256, 4) void k_fused(
    float* __restrict__ h, const float* S, const int* __restrict__ cnt,
    const float* __restrict__ W2, const float* __restrict__ b2,
    const float* __restrict__ W1n, const float* __restrict__ b1n,
    float* P, float* Q, int N)
{
    __shared__ float lds[64 * LROW];
    int bn0 = blockIdx.x * 64;
    int t = threadIdx.x;
    stage_tile(lds, S, bn0, N, t);
    __syncthreads();
    int tx = t & 15, ty = t >> 4;
    int j0 = tx * 8, n0 = ty * 4;
    float acc[4][8];
    #pragma unroll
    for (int a = 0; a < 4; ++a)
        #pragma unroll
        for (int b = 0; b < 8; ++b) acc[a][b] = 0.f;
    gemm4x8(lds, W2, acc, j0, n0);
    float hn[4][8];
    for (int nn = 0; nn < 4; ++nn) {
        int n = bn0 + n0 + nn;
        if (n < N) {
            int c = cnt[n];
            float4 h0 = *(float4*)&h[(size_t)n * 128 + j0];
            float4 h1 = *(float4*)&h[(size_t)n * 128 + j0 + 4];
            float hv[8] = {h0.x, h0.y, h0.z, h0.w, h1.x, h1.y, h1.z, h1.w};
            #pragma unroll
            for (int jj = 0; jj < 8; ++jj) {
                float agg = acc[nn][jj] + b2[j0 + jj];
                float r = (c > 0) ? fmaxf(agg, 0.f) : 0.f;
                hn[nn][jj] = hv[jj] + r;
            }
            float4 o0 = {hn[nn][0], hn[nn][1], hn[nn][2], hn[nn][3]};
            float4 o1 = {hn[nn][4], hn[nn][5], hn[nn][6], hn[nn][7]};
            *(float4*)&h[(size_t)n * 128 + j0] = o0;
            *(float4*)&h[(size_t)n * 128 + j0 + 4] = o1;
        } else {
            #pragma unroll
            for (int jj = 0; jj < 8; ++jj) hn[nn][jj] = 0.f;
        }
    }
    __syncthreads();  // S-tile reads done
    #pragma unroll
    for (int nn = 0; nn < 4; ++nn) {
        float4 o0 = {hn[nn][0], hn[nn][1], hn[nn][2], hn[nn][3]};
        float4 o1 = {hn[nn][4], hn[nn][5], hn[nn][6], hn[nn][7]};
        *(float4*)&lds[(n0 + nn) * LROW + j0] = o0;
        *(float4*)&lds[(n0 + nn) * LROW + j0 + 4] = o1;
    }
    __syncthreads();
    pq_phase(lds, W1n, b1n, P, Q, bn0, N, t);
}

// ---------- final: h += relu(S@W2 + b2) then out = mlp2(h, out_w*, out_b*) ----------
__global__ __launch_bounds__(256, 4) void k_final(
    const float* __restrict__ h, const float* S, const int* __restrict__ cnt,
    const float* __restrict__ W2, const float* __restrict__ b2,
    const float* __restrict__ ow1, const float* __restrict__ ob1,
    const float* __restrict__ ow2, const float* __restrict__ ob2,
    float* __restrict__ out, int N)
{
    __shared__ float lds[64 * LROW];
    int bn0 = blockIdx.x * 64;
    int t = threadIdx.x;
    stage_tile(lds, S, bn0, N, t);
    __syncthreads();
    int tx = t & 15, ty = t >> 4;
    int j0 = tx * 8, n0 = ty * 4;
    float acc[4][8];
    #pragma unroll
    for (int a = 0; a < 4; ++a)
        #pragma unroll
        for (int b = 0; b < 8; ++b) acc[a][b] = 0.f;
    gemm4x8(lds, W2, acc, j0, n0);
    float hn[4][8];
    for (int nn = 0; nn < 4; ++nn) {
        int n = bn0 + n0 + nn;
        if (n < N) {
            int c = cnt[n];
            float4 h0 = *(const float4*)&h[(size_t)n * 128 + j0];
            float4 h1 = *(const float4*)&h[(size_t)n * 128 + j0 + 4];
            float hv[8] = {h0.x, h0.y, h0.z, h0.w, h1.x, h1.y, h1.z, h1.w};
            #pragma unroll
            for (int jj = 0; jj < 8; ++jj) {
                float agg = acc[nn][jj] + b2[j0 + jj];
                float r = (c > 0) ? fmaxf(agg, 0.f) : 0.f;
                hn[nn][jj] = hv[jj] + r;
            }
        } else {
            #pragma unroll
            for (int jj = 0; jj < 8; ++jj) hn[nn][jj] = 0.f;
        }
    }
    __syncthreads();
    #pragma unroll
    for (int nn = 0; nn < 4; ++nn) {
        float4 o0 = {hn[nn][0], hn[nn][1], hn[nn][2], hn[nn][3]};
        float4 o1 = {hn[nn][4], hn[nn][5], hn[nn][6], hn[nn][7]};
        *(float4*)&lds[(n0 + nn) * LROW + j0] = o0;
        *(float4*)&lds[(n0 + nn) * LROW + j0 + 4] = o1;
    }
    __syncthreads();
    // hidden = relu(h @ ow1 + ob1)
    float acc2[4][8];
    #pragma unroll
    for (int a = 0; a < 4; ++a)
        #pragma unroll
        for (int b = 0; b < 8; ++b) acc2[a][b] = 0.f;
    gemm4x8(lds, ow1, acc2, j0, n0);
    __syncthreads();
    #pragma unroll
    for (int nn = 0; nn < 4; ++nn) {
        float4 o0 = {fmaxf(acc2[nn][0] + ob1[j0 + 0], 0.f), fmaxf(acc2[nn][1] + ob1[j0 + 1], 0.f),
                     fmaxf(acc2[nn][2] + ob1[j0 + 2], 0.f), fmaxf(acc2[nn][3] + ob1[j0 + 3], 0.f)};
        float4 o1 = {fmaxf(acc2[nn][4] + ob1[j0 + 4], 0.f), fmaxf(acc2[nn][5] + ob1[j0 + 5], 0.f),
                     fmaxf(acc2[nn][6] + ob1[j0 + 6], 0.f), fmaxf(acc2[nn][7] + ob1[j0 + 7], 0.f)};
        *(float4*)&lds[(n0 + nn) * LROW + j0] = o0;
        *(float4*)&lds[(n0 + nn) * LROW + j0 + 4] = o1;
    }
    __syncthreads();
    if (t < 192) {
        int nn = t / 3, d = t - nn * 3;
        int n = bn0 + nn;
        if (n < N) {
            float s = ob2[d];
            for (int j = 0; j < 128; ++j) s += lds[nn * LROW + j] * ow2[j * 3 + d];
            out[(size_t)n * 3 + d] = s;
        }
    }
}

extern "C" void kernel_launch(void* const* d_in, const int* in_sizes, int n_in,
                              void* d_out, int out_size, void* d_ws, size_t ws_size,
                              hipStream_t stream)
{
    const float* x         = (const float*)d_in[0];
    const int*   edge_idx  = (const int*)d_in[1];
    const float* edge_attr = (const float*)d_in[2];
    const float* tt        = (const float*)d_in[3];
    const int*   batch     = (const int*)d_in[4];
    const float* cond      = (const float*)d_in[5];
    const float* in_w1 = (const float*)d_in[6],  *in_b1 = (const float*)d_in[7];
    const float* in_w2 = (const float*)d_in[8],  *in_b2 = (const float*)d_in[9];
    const float* t_w1  = (const float*)d_in[10], *t_b1  = (const float*)d_in[11];
    const float* t_w2  = (const float*)d_in[12], *t_b2  = (const float*)d_in[13];
    const float* c_w1  = (const float*)d_in[14], *c_b1  = (const float*)d_in[15];
    const float* c_w2  = (const float*)d_in[16], *c_b2  = (const float*)d_in[17];
    const float* convW1 = (const float*)d_in[18], *convb1 = (const float*)d_in[19];
    const float* convW2 = (const float*)d_in[20], *convb2 = (const float*)d_in[21];
    const float* out_w1 = (const float*)d_in[22], *out_b1 = (const float*)d_in[23];
    const float* out_w2 = (const float*)d_in[24], *out_b2 = (const float*)d_in[25];

    const int N = in_sizes[0] / 3;
    const int E = in_sizes[1] / 2;
    const int B = in_sizes[3];
    const int CDIM = in_sizes[5] / B;
    const int L = in_sizes[19] / 128;

    const int* esrc = edge_idx;
    const int* edst = edge_idx + E;

    char* w = (char*)d_ws;
    auto alloc = [&](size_t bytes) -> char* {
        char* p = w;
        w += (bytes + 255) & ~(size_t)255;
        return p;
    };
    float* h    = (float*)alloc((size_t)N * 128 * 4);
    float* P    = (float*)alloc((size_t)N * 128 * 4);   // also S (aliased)
    float* Q    = (float*)alloc((size_t)N * 128 * 4);
    int*   cnt  = (int*)alloc((size_t)N * 4);
    int*   cur  = (int*)alloc((size_t)N * 4);
    int*   off  = (int*)alloc((size_t)N * 4);
    int*   bsum = (int*)alloc(4096);
    int*   boff = (int*)alloc(4096);
    int2*  csr  = (int2*)alloc((size_t)E * 8);
    float* tf   = (float*)alloc((size_t)B * 128 * 4);
    float* cf   = (float*)alloc((size_t)B * 128 * 4);

    hipMemsetAsync(cnt, 0, (size_t)N * 4, stream);
    hipMemsetAsync(cur, 0, (size_t)N * 4, stream);

    k_tc<<<1, 128, 0, stream>>>(tt, cond, t_w1, t_b1, t_w2, t_b2,
                                c_w1, c_b1, c_w2, c_b2, tf, cf, B, CDIM);

    const int eb = (E + 255) / 256;
    const int nb = (N + 255) / 256;
    k_count<<<eb, 256, 0, stream>>>(edst, cnt, E);
    k_scan1<<<nb, 256, 0, stream>>>(cnt, bsum, N);
    k_scan2<<<1, 512, 0, stream>>>(bsum, boff, nb);
    k_scan3<<<nb, 256, 0, stream>>>(cnt, boff, off, N);
    k_fill<<<eb, 256, 0, stream>>>(esrc, edst, edge_attr, off, cur, csr, E);

    const int gnodes = (N + 63) / 64;
    k_input_pq<<<gnodes, 256, 0, stream>>>(x, batch, in_w1, in_b1, in_w2, in_b2,
                                           tf, cf, convW1, convb1, h, P, Q, N);

    for (int i = 0; i < L; ++i) {
        const float* W1 = convW1 + (size_t)i * 257 * 128;
        const float* b1 = convb1 + (size_t)i * 128;
        const float* W2 = convW2 + (size_t)i * 128 * 128;
        const float* b2 = convb2 + (size_t)i * 128;
        k_edge<<<(N + 3) / 4, 256, 0, stream>>>(P, Q, csr, off, cnt, W1, N);
        if (i < L - 1) {
            const float* W1n = convW1 + (size_t)(i + 1) * 257 * 128;
            const float* b1n = convb1 + (size_t)(i + 1) * 128;
            k_fused<<<gnodes, 256, 0, stream>>>(h, P, cnt, W2, b2, W1n, b1n, P, Q, N);
        } else {
            k_final<<<gnodes, 256, 0, stream>>>(h, P, cnt, W2, b2,
                                                out_w1, out_b1, out_w2, out_b2,
                                                (float*)d_out, N);
        }
    }
}